// Round 1
// baseline (174.513 us; speedup 1.0000x reference)
//
#include <hip/hip_runtime.h>
#include <math.h>

#define HW   4096
#define NC   64
#define NB   2
#define NHD  4
#define DH   16
#define NBH  (NB*NHD)

// ---------------------------------------------------------------------------
// Kernel A: per-pixel 1x1 convs: qkv = W_qkv x + b, illu = W_illu f + b.
// Q pre-scaled by d^-0.5 = 0.25; K = k + illu fused here.
// Layout out: Q/K/V [bh][p][dd], bh = b*4 + head.
// grid 256 blocks x 192 threads (3 waves: q-wave, k-wave, v-wave).
// ---------------------------------------------------------------------------
__global__ __launch_bounds__(192) void qkv_kernel(
    const float* __restrict__ x, const float* __restrict__ illu,
    const float* __restrict__ qkv_w, const float* __restrict__ qkv_b,
    const float* __restrict__ illu_w, const float* __restrict__ illu_b,
    float* __restrict__ Q, float* __restrict__ K, float* __restrict__ V)
{
    const int PIX = 32;
    __shared__ float xs[PIX][NC];
    __shared__ float fs[PIX][NC];
    int blk = blockIdx.x;            // 256 blocks
    int b   = blk >> 7;              // 128 blocks per batch image
    int p0  = (blk & 127) * PIX;
    int tid = threadIdx.x;

    for (int idx = tid; idx < PIX*NC; idx += 192) {
        int ch = idx >> 5;           // idx = ch*32 + pp  (coalesced over pp)
        int pp = idx & 31;
        xs[pp][ch] = x   [(b*NC + ch)*HW + p0 + pp];
        fs[pp][ch] = illu[(b*NC + ch)*HW + p0 + pp];
    }

    int role = tid / 64;             // 0 = q, 1 = k, 2 = v  (wave-uniform)
    int co   = tid & 63;             // channel within group = head*16+dd
    int head = co >> 4;
    int dd   = co & 15;
    int bh   = b*NHD + head;

    // qkv weight row = tid (q rows 0..63, k rows 64..127, v rows 128..191)
    float wq[NC];
    #pragma unroll
    for (int c4 = 0; c4 < NC/4; c4++) {
        float4 w = ((const float4*)(qkv_w + tid*NC))[c4];
        wq[4*c4+0] = w.x; wq[4*c4+1] = w.y; wq[4*c4+2] = w.z; wq[4*c4+3] = w.w;
    }
    float bias = qkv_b[tid];
    float wi[NC];
    if (role == 1) {
        #pragma unroll
        for (int c4 = 0; c4 < NC/4; c4++) {
            float4 w = ((const float4*)(illu_w + co*NC))[c4];
            wi[4*c4+0] = w.x; wi[4*c4+1] = w.y; wi[4*c4+2] = w.z; wi[4*c4+3] = w.w;
        }
        bias += illu_b[co];
    }

    float* outp = (role == 0) ? Q : (role == 1 ? K : V);
    float  sc   = (role == 0) ? 0.25f : 1.0f;   // fold softmax scale into q
    __syncthreads();

    for (int pp = 0; pp < PIX; pp++) {
        float a0 = 0.f, a1 = 0.f, a2 = 0.f, a3 = 0.f;
        #pragma unroll
        for (int c4 = 0; c4 < NC/4; c4++) {
            float4 xv = ((const float4*)xs[pp])[c4];
            a0 = fmaf(wq[4*c4+0], xv.x, a0);
            a1 = fmaf(wq[4*c4+1], xv.y, a1);
            a2 = fmaf(wq[4*c4+2], xv.z, a2);
            a3 = fmaf(wq[4*c4+3], xv.w, a3);
        }
        float acc = bias + ((a0 + a1) + (a2 + a3));
        if (role == 1) {
            float b0 = 0.f, b1 = 0.f, b2 = 0.f, b3 = 0.f;
            #pragma unroll
            for (int c4 = 0; c4 < NC/4; c4++) {
                float4 iv = ((const float4*)fs[pp])[c4];
                b0 = fmaf(wi[4*c4+0], iv.x, b0);
                b1 = fmaf(wi[4*c4+1], iv.y, b1);
                b2 = fmaf(wi[4*c4+2], iv.z, b2);
                b3 = fmaf(wi[4*c4+3], iv.w, b3);
            }
            acc += ((b0 + b1) + (b2 + b3));
        }
        outp[(size_t)bh*HW*DH + (size_t)(p0+pp)*DH + dd] = acc * sc;
    }
}

// ---------------------------------------------------------------------------
// Kernel B: flash attention, fp32 SIMT.
// 256 blocks (8 bh x 32 row-blocks of 128 rows). 256 threads = 4 waves.
// Wave s handles key split s (1024 keys); lane owns 2 q-rows.
// No max-subtraction: logits bounded (|q.k/4| << 88), softmax shift-invariant.
// Split partials (acc[16], l) merged through LDS.
// ---------------------------------------------------------------------------
#define TS       128     // keys per LDS tile per split
#define SPLITS   4
#define ROWS_PB  128
#define KEYS_PS  1024

__global__ __launch_bounds__(256) void attn_kernel(
    const float* __restrict__ Q, const float* __restrict__ K,
    const float* __restrict__ V, float* __restrict__ O)
{
    __shared__ float smem[16384];            // 64KB; staging then merge
    float* Ks = smem;                        // [SPLITS][TS][DH] = 8192 floats
    float* Vs = smem + SPLITS*TS*DH;         // 8192 floats

    int blk  = blockIdx.x;                   // 256
    int bh   = blk >> 5;
    int row0 = (blk & 31) * ROWS_PB;
    int tid  = threadIdx.x;
    int s    = tid >> 6;                     // split = wave id
    int lane = tid & 63;
    int rl   = lane * 2;                     // local row (2 rows per lane)

    const float* Qb = Q + (size_t)bh*HW*DH;
    const float* Kb = K + (size_t)bh*HW*DH;
    const float* Vb = V + (size_t)bh*HW*DH;

    float q0[16], q1[16];
    {
        const float4* qp = (const float4*)(Qb + (size_t)(row0 + rl)*DH);
        #pragma unroll
        for (int i = 0; i < 4; i++) {
            float4 a = qp[i];
            q0[4*i+0] = a.x; q0[4*i+1] = a.y; q0[4*i+2] = a.z; q0[4*i+3] = a.w;
            float4 c = qp[4+i];
            q1[4*i+0] = c.x; q1[4*i+1] = c.y; q1[4*i+2] = c.z; q1[4*i+3] = c.w;
        }
    }
    float acc0[16], acc1[16];
    #pragma unroll
    for (int i = 0; i < 16; i++) { acc0[i] = 0.f; acc1[i] = 0.f; }
    float l0 = 0.f, l1 = 0.f;

    for (int t = 0; t < KEYS_PS/TS; t++) {
        __syncthreads();                      // previous tile fully consumed
        // stage K,V for all 4 splits: 2048 float4 each, 8 per thread
        #pragma unroll
        for (int j = 0; j < 8; j++) {
            int f   = tid + j*256;            // 0..2047
            int sp  = f >> 9;                 // 512 float4 per split
            int rem = f & 511;
            int kk  = rem >> 2;
            int d4  = rem & 3;
            int gk  = sp*KEYS_PS + t*TS + kk;
            ((float4*)Ks)[f] = ((const float4*)(Kb + (size_t)gk*DH))[d4];
            ((float4*)Vs)[f] = ((const float4*)(Vb + (size_t)gk*DH))[d4];
        }
        __syncthreads();
        const float* Kt = Ks + s*TS*DH;
        const float* Vt = Vs + s*TS*DH;
        for (int kk = 0; kk < TS; kk++) {
            float ka[16];
            #pragma unroll
            for (int i = 0; i < 4; i++) {
                float4 kv = ((const float4*)(Kt + kk*DH))[i];
                ka[4*i+0] = kv.x; ka[4*i+1] = kv.y; ka[4*i+2] = kv.z; ka[4*i+3] = kv.w;
            }
            float s0e = 0.f, s0o = 0.f, s1e = 0.f, s1o = 0.f;
            #pragma unroll
            for (int i = 0; i < 8; i++) {
                s0e = fmaf(q0[2*i],   ka[2*i],   s0e);
                s0o = fmaf(q0[2*i+1], ka[2*i+1], s0o);
                s1e = fmaf(q1[2*i],   ka[2*i],   s1e);
                s1o = fmaf(q1[2*i+1], ka[2*i+1], s1o);
            }
            float p0 = __expf(s0e + s0o);
            float p1 = __expf(s1e + s1o);
            l0 += p0; l1 += p1;
            #pragma unroll
            for (int i = 0; i < 4; i++) {
                float4 vv = ((const float4*)(Vt + kk*DH))[i];
                acc0[4*i+0] = fmaf(p0, vv.x, acc0[4*i+0]);
                acc0[4*i+1] = fmaf(p0, vv.y, acc0[4*i+1]);
                acc0[4*i+2] = fmaf(p0, vv.z, acc0[4*i+2]);
                acc0[4*i+3] = fmaf(p0, vv.w, acc0[4*i+3]);
                acc1[4*i+0] = fmaf(p1, vv.x, acc1[4*i+0]);
                acc1[4*i+1] = fmaf(p1, vv.y, acc1[4*i+1]);
                acc1[4*i+2] = fmaf(p1, vv.z, acc1[4*i+2]);
                acc1[4*i+3] = fmaf(p1, vv.w, acc1[4*i+3]);
            }
        }
    }

    // ---- merge splits through LDS: layout [s][row_local][17] (17: acc16 + l)
    __syncthreads();
    float* mg = smem;                         // 4*128*17 = 8704 floats
    {
        float* d0 = mg + (s*ROWS_PB + rl    )*17;
        float* d1 = mg + (s*ROWS_PB + rl + 1)*17;
        #pragma unroll
        for (int i = 0; i < 16; i++) { d0[i] = acc0[i]; d1[i] = acc1[i]; }
        d0[16] = l0; d1[16] = l1;
    }
    __syncthreads();
    if (tid < ROWS_PB) {
        int row = tid;
        float ot[16];
        #pragma unroll
        for (int i = 0; i < 16; i++) ot[i] = 0.f;
        float lt = 0.f;
        #pragma unroll
        for (int sp = 0; sp < SPLITS; sp++) {
            const float* src = mg + (sp*ROWS_PB + row)*17;
            #pragma unroll
            for (int i = 0; i < 16; i++) ot[i] += src[i];
            lt += src[16];
        }
        float inv = 1.0f / lt;
        float4* op = (float4*)(O + (size_t)bh*HW*DH + (size_t)(row0+row)*DH);
        #pragma unroll
        for (int i = 0; i < 4; i++) {
            float4 o4;
            o4.x = ot[4*i+0]*inv; o4.y = ot[4*i+1]*inv;
            o4.z = ot[4*i+2]*inv; o4.w = ot[4*i+3]*inv;
            op[i] = o4;
        }
    }
}

// ---------------------------------------------------------------------------
// Kernel C: proj 1x1 conv + output transpose to [b][c][p].
// grid 256 blocks x 256 threads; 32 pixels per block.
// ---------------------------------------------------------------------------
__global__ __launch_bounds__(256) void proj_kernel(
    const float* __restrict__ O, const float* __restrict__ proj_w,
    const float* __restrict__ proj_b, float* __restrict__ y)
{
    const int PIX = 32;
    __shared__ float os[PIX][NC];
    __shared__ float ys[NC][PIX+1];
    int blk = blockIdx.x;            // 256
    int b   = blk >> 7;
    int p0  = (blk & 127) * PIX;
    int tid = threadIdx.x;
    int c   = tid & 63;
    int pg  = tid >> 6;              // 0..3

    for (int idx = tid; idx < PIX*NC; idx += 256) {
        int pp = idx >> 6;           // idx = pp*64 + c'
        int cp = idx & 63;
        os[pp][cp] = O[((size_t)(b*NHD + (cp>>4)))*HW*DH + (size_t)(p0+pp)*DH + (cp & 15)];
    }
    float w[NC];
    #pragma unroll
    for (int c4 = 0; c4 < NC/4; c4++) {
        float4 wv = ((const float4*)(proj_w + c*NC))[c4];
        w[4*c4+0] = wv.x; w[4*c4+1] = wv.y; w[4*c4+2] = wv.z; w[4*c4+3] = wv.w;
    }
    float bias = proj_b[c];
    __syncthreads();

    for (int pi = pg; pi < PIX; pi += 4) {
        float a0 = 0.f, a1 = 0.f, a2 = 0.f, a3 = 0.f;
        #pragma unroll
        for (int c4 = 0; c4 < NC/4; c4++) {
            float4 ov = ((const float4*)os[pi])[c4];
            a0 = fmaf(w[4*c4+0], ov.x, a0);
            a1 = fmaf(w[4*c4+1], ov.y, a1);
            a2 = fmaf(w[4*c4+2], ov.z, a2);
            a3 = fmaf(w[4*c4+3], ov.w, a3);
        }
        ys[c][pi] = bias + ((a0 + a1) + (a2 + a3));
    }
    __syncthreads();
    for (int idx = tid; idx < PIX*NC; idx += 256) {
        int cc = idx >> 5;           // idx = cc*32 + i
        int i  = idx & 31;
        y[(size_t)(b*NC + cc)*HW + p0 + i] = ys[cc][i];
    }
}

// ---------------------------------------------------------------------------
extern "C" void kernel_launch(void* const* d_in, const int* in_sizes, int n_in,
                              void* d_out, int out_size, void* d_ws, size_t ws_size,
                              hipStream_t stream)
{
    const float* x      = (const float*)d_in[0];
    const float* illu   = (const float*)d_in[1];
    const float* qkv_w  = (const float*)d_in[2];
    const float* qkv_b  = (const float*)d_in[3];
    const float* illu_w = (const float*)d_in[4];
    const float* illu_b = (const float*)d_in[5];
    const float* proj_w = (const float*)d_in[6];
    const float* proj_b = (const float*)d_in[7];
    float* out = (float*)d_out;

    float* Q = (float*)d_ws;                 // each: 8*4096*16 floats = 2MB
    float* K = Q + (size_t)NBH*HW*DH;
    float* V = K + (size_t)NBH*HW*DH;
    float* O = V + (size_t)NBH*HW*DH;        // total 8MB of ws

    hipLaunchKernelGGL(qkv_kernel, dim3(256), dim3(192), 0, stream,
                       x, illu, qkv_w, qkv_b, illu_w, illu_b, Q, K, V);
    hipLaunchKernelGGL(attn_kernel, dim3(256), dim3(256), 0, stream,
                       Q, K, V, O);
    hipLaunchKernelGGL(proj_kernel, dim3(256), dim3(256), 0, stream,
                       O, proj_w, proj_b, out);
}

// Round 3
// 114.101 us; speedup vs baseline: 1.5295x; 1.5295x over previous
//
#include <hip/hip_runtime.h>
#include <hip/hip_bf16.h>
#include <math.h>

#define HW   4096
#define NC   64
#define NB   2
#define NHD  4
#define DH   16
#define NBH  (NB*NHD)

typedef __attribute__((ext_vector_type(4))) float f32x4;
typedef __attribute__((ext_vector_type(4))) int   int4v;
typedef __attribute__((ext_vector_type(2))) unsigned int uint2v;

#define QSCALE 0.36067376022224087f   // 0.25 * log2(e)

static __device__ __forceinline__ unsigned short bf16_bits(float f) {
    union { __hip_bfloat16 h; unsigned short u; } cv;
    cv.h = __float2bfloat16(f);
    return cv.u;
}
static __device__ __forceinline__ float bits_to_f(unsigned short b) {
    return __uint_as_float(((unsigned int)b) << 16);
}

static __device__ __forceinline__ void mfma_bf16_16x16x32(f32x4& acc, int4v a, int4v b) {
    asm volatile("v_mfma_f32_16x16x32_bf16 %0, %1, %2, %0"
                 : "+v"(acc) : "v"(a), "v"(b));
}

// ---------------------------------------------------------------------------
// Kernel A: qkv + illu 1x1 convs.
// Q (pre-scaled by 0.25*log2e) and K (= k+illu) stored as DOUBLE-BF16:
//   Qx/Kx layout [bh][p][32]: d0-15 = hi, d16-31 = lo residual.
// V stored single bf16, transposed: Vt [bh][d][key].
// ---------------------------------------------------------------------------
__global__ __launch_bounds__(192) void qkv_kernel(
    const float* __restrict__ x, const float* __restrict__ illu,
    const float* __restrict__ qkv_w, const float* __restrict__ qkv_b,
    const float* __restrict__ illu_w, const float* __restrict__ illu_b,
    ushort* __restrict__ Qx, ushort* __restrict__ Kx, ushort* __restrict__ Vt)
{
    const int PIX = 32;
    __shared__ float xs[PIX][NC];
    __shared__ float fs[PIX][NC];
    __shared__ ushort vs[NC][PIX];
    int blk = blockIdx.x;                // 256 blocks
    int b   = blk >> 7;
    int p0  = (blk & 127) * PIX;
    int tid = threadIdx.x;

    for (int idx = tid; idx < PIX*NC; idx += 192) {
        int ch = idx >> 5;
        int pp = idx & 31;
        xs[pp][ch] = x   [(b*NC + ch)*HW + p0 + pp];
        fs[pp][ch] = illu[(b*NC + ch)*HW + p0 + pp];
    }

    int role = tid / 64;                 // 0=q 1=k 2=v
    int co   = tid & 63;                 // head*16 + dd
    int head = co >> 4;
    int dd   = co & 15;
    int bh   = b*NHD + head;

    float wq[NC];
    #pragma unroll
    for (int c4 = 0; c4 < NC/4; c4++) {
        float4 w = ((const float4*)(qkv_w + tid*NC))[c4];
        wq[4*c4+0] = w.x; wq[4*c4+1] = w.y; wq[4*c4+2] = w.z; wq[4*c4+3] = w.w;
    }
    float bias = qkv_b[tid];
    float wi[NC];
    if (role == 1) {
        #pragma unroll
        for (int c4 = 0; c4 < NC/4; c4++) {
            float4 w = ((const float4*)(illu_w + co*NC))[c4];
            wi[4*c4+0] = w.x; wi[4*c4+1] = w.y; wi[4*c4+2] = w.z; wi[4*c4+3] = w.w;
        }
        bias += illu_b[co];
    }
    __syncthreads();

    for (int pp = 0; pp < PIX; pp++) {
        float a0 = 0.f, a1 = 0.f, a2 = 0.f, a3 = 0.f;
        #pragma unroll
        for (int c4 = 0; c4 < NC/4; c4++) {
            float4 xv = ((const float4*)xs[pp])[c4];
            a0 = fmaf(wq[4*c4+0], xv.x, a0);
            a1 = fmaf(wq[4*c4+1], xv.y, a1);
            a2 = fmaf(wq[4*c4+2], xv.z, a2);
            a3 = fmaf(wq[4*c4+3], xv.w, a3);
        }
        float acc = bias + ((a0 + a1) + (a2 + a3));
        if (role == 1) {
            float b0 = 0.f, b1 = 0.f, b2 = 0.f, b3 = 0.f;
            #pragma unroll
            for (int c4 = 0; c4 < NC/4; c4++) {
                float4 iv = ((const float4*)fs[pp])[c4];
                b0 = fmaf(wi[4*c4+0], iv.x, b0);
                b1 = fmaf(wi[4*c4+1], iv.y, b1);
                b2 = fmaf(wi[4*c4+2], iv.z, b2);
                b3 = fmaf(wi[4*c4+3], iv.w, b3);
            }
            acc += ((b0 + b1) + (b2 + b3));
        }
        size_t pidx = (size_t)bh*HW*32 + (size_t)(p0+pp)*32 + dd;
        if (role == 0) {
            float v = acc * QSCALE;
            unsigned short hb = bf16_bits(v);
            Qx[pidx]      = hb;
            Qx[pidx + 16] = bf16_bits(v - bits_to_f(hb));
        } else if (role == 1) {
            unsigned short hb = bf16_bits(acc);
            Kx[pidx]      = hb;
            Kx[pidx + 16] = bf16_bits(acc - bits_to_f(hb));
        } else {
            vs[co][pp] = bf16_bits(acc);
        }
    }
    __syncthreads();
    for (int idx = tid; idx < NC*PIX/2; idx += 192) {
        int row = idx >> 4;
        int j   = idx & 15;
        unsigned int val = *(const unsigned int*)&vs[row][2*j];
        ((unsigned int*)(Vt + ((size_t)(b*NC + row))*HW + p0))[j] = val;
    }
}

// ---------------------------------------------------------------------------
// Kernel B: MFMA flash attention, double-bf16 precision.
// 512 blocks = 8 bh x 64 q-blocks(64 rows). 4 waves x 16 q-rows each.
// Swapped QK^T: mfma(K,Q). A-fragment slots 0-15 = K_hi, 16-31 = K_lo;
// B1 = [Q_hi|Q_hi], B2 = [Q_lo|Q_lo] -> exact (Khi+Klo)(Qhi+Qlo).
// P split hi/lo for PV (2 MFMAs). No-max softmax (logits bounded, exact).
// ---------------------------------------------------------------------------
#define KT 128

__global__ __launch_bounds__(256, 2) void attn_kernel(
    const ushort* __restrict__ Qx, const ushort* __restrict__ Kx,
    const ushort* __restrict__ Vt, float* __restrict__ O)
{
    __shared__ alignas(16) ushort Ks[128*32];   // [row][slot*8] XOR-swizzled, 8KB
    __shared__ alignas(16) ushort Vs[16*136];   // [d][136 pad]  4.25KB

    int blk  = blockIdx.x;               // 512
    int bh   = blk >> 6;
    int q0   = (blk & 63) * 64;
    int tid  = threadIdx.x;
    int w    = tid >> 6;
    int lane = tid & 63;
    int g    = lane >> 4;                // lane group 0..3
    int qc   = lane & 15;                // query col / A-row / V d-col

    const ushort* Qb = Qx + (size_t)bh*HW*32;
    const ushort* Kb = Kx + (size_t)bh*HW*32;
    const ushort* Vb = Vt + (size_t)bh*DH*HW;

    // Q fragments: B1 = Q_hi[d=8(g&1)..+7] (dup for g>=2), B2 = Q_lo likewise
    int qrow = q0 + w*16 + qc;
    int4v qhi = *(const int4v*)(Qb + (size_t)qrow*32 +      8*(g&1));
    int4v qlo = *(const int4v*)(Qb + (size_t)qrow*32 + 16 + 8*(g&1));

    f32x4 oacc = {0.f, 0.f, 0.f, 0.f};
    float l = 0.f;

    int sV_d = tid >> 4, sV_seg = tid & 15;

    for (int t = 0; t < HW/KT; ++t) {
        __syncthreads();
        int kt = t * KT;
        // stage K tile: 128 rows x 32 (hi|lo), 512 16B-chunks, 2 per thread
        #pragma unroll
        for (int j = 0; j < 2; ++j) {
            int f = tid + j*256;
            int r = f >> 2, h = f & 3;
            int m = (r & 3) ^ ((r >> 2) & 3);
            int4v kv = *(const int4v*)(Kb + (size_t)(kt + r)*32 + 8*h);
            *(int4v*)(Ks + r*32 + (h ^ m)*8) = kv;
        }
        // stage V^T tile: 16 d-rows x 128 keys
        int4v vv = *(const int4v*)(Vb + (size_t)sV_d*HW + kt + sV_seg*8);
        *(int4v*)(Vs + sV_d*136 + sV_seg*8) = vv;
        __syncthreads();

        unsigned int ph0=0, ph1=0, ph2=0, ph3=0;
        unsigned int pl0=0, pl1=0, pl2=0, pl3=0;
        #pragma unroll
        for (int kb = 0; kb < 8; ++kb) {
            int krow = kb*16 + qc;
            int m    = (krow & 3) ^ ((krow >> 2) & 3);
            int4v kfrag = *(const int4v*)(Ks + krow*32 + (g ^ m)*8);
            f32x4 s = {0.f, 0.f, 0.f, 0.f};
            mfma_bf16_16x16x32(s, kfrag, qhi);
            mfma_bf16_16x16x32(s, kfrag, qlo);   // S[key=4g+r][q=qc], ~fp32 exact
            float p0 = exp2f(s.x), p1 = exp2f(s.y);
            float p2 = exp2f(s.z), p3 = exp2f(s.w);
            l += (p0 + p1) + (p2 + p3);
            unsigned short h0 = bf16_bits(p0), h1 = bf16_bits(p1);
            unsigned short h2 = bf16_bits(p2), h3 = bf16_bits(p3);
            unsigned int hlo = (unsigned int)h0 | ((unsigned int)h1 << 16);
            unsigned int hhi = (unsigned int)h2 | ((unsigned int)h3 << 16);
            unsigned int llo = (unsigned int)bf16_bits(p0 - bits_to_f(h0))
                             | ((unsigned int)bf16_bits(p1 - bits_to_f(h1)) << 16);
            unsigned int lhi = (unsigned int)bf16_bits(p2 - bits_to_f(h2))
                             | ((unsigned int)bf16_bits(p3 - bits_to_f(h3)) << 16);
            if ((kb & 1) == 0) { ph0 = hlo; ph1 = hhi; pl0 = llo; pl1 = lhi; }
            else {
                ph2 = hlo; ph3 = hhi; pl2 = llo; pl3 = lhi;
                int kE = (kb-1)*16 + 4*g;
                int kO = kb*16     + 4*g;
                uint2v vE = *(const uint2v*)(Vs + qc*136 + kE);
                uint2v vO = *(const uint2v*)(Vs + qc*136 + kO);
                int4v bfr; bfr.x = (int)vE.x; bfr.y = (int)vE.y;
                           bfr.z = (int)vO.x; bfr.w = (int)vO.y;
                int4v ah; ah.x = (int)ph0; ah.y = (int)ph1; ah.z = (int)ph2; ah.w = (int)ph3;
                int4v al; al.x = (int)pl0; al.y = (int)pl1; al.z = (int)pl2; al.w = (int)pl3;
                mfma_bf16_16x16x32(oacc, ah, bfr);  // O[q=4g+r][d=qc]
                mfma_bf16_16x16x32(oacc, al, bfr);
            }
        }
    }

    l += __shfl_xor(l, 16);
    l += __shfl_xor(l, 32);

    float* Ob = O + ((size_t)bh*HW + q0 + w*16) * DH;
    #pragma unroll
    for (int r = 0; r < 4; ++r) {
        float lr = __shfl(l, 4*g + r);
        float ov = (r==0? oacc.x : r==1? oacc.y : r==2? oacc.z : oacc.w);
        Ob[(4*g + r)*DH + qc] = ov / lr;
    }
}

// ---------------------------------------------------------------------------
// Kernel C: proj 1x1 conv + output transpose to [b][c][p].
// ---------------------------------------------------------------------------
__global__ __launch_bounds__(256) void proj_kernel(
    const float* __restrict__ O, const float* __restrict__ proj_w,
    const float* __restrict__ proj_b, float* __restrict__ y)
{
    const int PIX = 32;
    __shared__ float os[PIX][NC];
    __shared__ float ys[NC][PIX+1];
    int blk = blockIdx.x;
    int b   = blk >> 7;
    int p0  = (blk & 127) * PIX;
    int tid = threadIdx.x;
    int c   = tid & 63;
    int pg  = tid >> 6;

    for (int idx = tid; idx < PIX*NC; idx += 256) {
        int pp = idx >> 6;
        int cp = idx & 63;
        os[pp][cp] = O[((size_t)(b*NHD + (cp>>4)))*HW*DH + (size_t)(p0+pp)*DH + (cp & 15)];
    }
    float wv[NC];
    #pragma unroll
    for (int c4 = 0; c4 < NC/4; c4++) {
        float4 t = ((const float4*)(proj_w + c*NC))[c4];
        wv[4*c4+0] = t.x; wv[4*c4+1] = t.y; wv[4*c4+2] = t.z; wv[4*c4+3] = t.w;
    }
    float bias = proj_b[c];
    __syncthreads();

    for (int pi = pg; pi < PIX; pi += 4) {
        float a0 = 0.f, a1 = 0.f, a2 = 0.f, a3 = 0.f;
        #pragma unroll
        for (int c4 = 0; c4 < NC/4; c4++) {
            float4 ov = ((const float4*)os[pi])[c4];
            a0 = fmaf(wv[4*c4+0], ov.x, a0);
            a1 = fmaf(wv[4*c4+1], ov.y, a1);
            a2 = fmaf(wv[4*c4+2], ov.z, a2);
            a3 = fmaf(wv[4*c4+3], ov.w, a3);
        }
        ys[c][pi] = bias + ((a0 + a1) + (a2 + a3));
    }
    __syncthreads();
    for (int idx = tid; idx < PIX*NC; idx += 256) {
        int cc = idx >> 5;
        int i  = idx & 31;
        y[(size_t)(b*NC + cc)*HW + p0 + i] = ys[cc][i];
    }
}

// ---------------------------------------------------------------------------
extern "C" void kernel_launch(void* const* d_in, const int* in_sizes, int n_in,
                              void* d_out, int out_size, void* d_ws, size_t ws_size,
                              hipStream_t stream)
{
    const float* x      = (const float*)d_in[0];
    const float* illu   = (const float*)d_in[1];
    const float* qkv_w  = (const float*)d_in[2];
    const float* qkv_b  = (const float*)d_in[3];
    const float* illu_w = (const float*)d_in[4];
    const float* illu_b = (const float*)d_in[5];
    const float* proj_w = (const float*)d_in[6];
    const float* proj_b = (const float*)d_in[7];
    float* out = (float*)d_out;

    ushort* Qx = (ushort*)d_ws;                     // 8*4096*32 bf16 = 2MB (hi|lo)
    ushort* Kx = Qx + (size_t)NBH*HW*32;            // 2MB (hi|lo)
    ushort* Vt = Kx + (size_t)NBH*HW*32;            // 1MB  [bh][d][key]
    float*  O  = (float*)(Vt + (size_t)NBH*HW*DH);  // 2MB fp32

    hipLaunchKernelGGL(qkv_kernel, dim3(256), dim3(192), 0, stream,
                       x, illu, qkv_w, qkv_b, illu_w, illu_b, Qx, Kx, Vt);
    hipLaunchKernelGGL(attn_kernel, dim3(512), dim3(256), 0, stream,
                       Qx, Kx, Vt, O);
    hipLaunchKernelGGL(proj_kernel, dim3(256), dim3(256), 0, stream,
                       O, proj_w, proj_b, out);
}